// Round 1
// baseline (1243.022 us; speedup 1.0000x reference)
//
#include <hip/hip_runtime.h>
#include <math.h>

// ---------------------------------------------------------------------------
// GCN 165->32->16->2 + log_softmax, N=100k, E=3.2M.
//
// Round 11 (scatter-aggregation redesign):
//  - DELETED: sort_kernel / esrc / rowptr / rowcnt / per-node gather loops.
//  - place_kernel (unchanged): packed (local<<24|src) into 8 subregions per
//    bucket with replicated cursors.
//  - degree_kernel: one counting pass over ebuf -> dinv. (replaces sort)
//  - agg_kernel<NF>: one block per bucket, 32KB LDS acc[NF][256], streams
//    packed edges coalesced, ds_add_f32 per feature (bank = l%32, random l
//    => ~2-way = free). Edge-parallel: no per-node loop imbalance, no esrc.
//  - gemm1 epilogue now writes [N][4]uint4 so each edge's 32 bf16 features
//    are ONE contiguous 64B read in agg1 (was 2x32B, 3.2MB apart).
//  - agg3_kernel fuses last scatter-agg + bias + log_softmax.
// ---------------------------------------------------------------------------

constexpr int NT = 256;
constexpr int NPB = 256;       // nodes per bucket (partition)
constexpr int LOG_NPB = 8;
constexpr int MAXBUK = 512;
constexpr int BSTRIDE = 10240; // edge slots per bucket (mean 8184)
constexpr int NREP = 8;        // cursor replicas / subregions per bucket
constexpr int SUB = BSTRIDE / NREP;  // 1280 slots per subregion
constexpr int EPB_B = 4096;    // edges per block, place pass
constexpr int AT = 512;        // threads per block, agg kernels

typedef __attribute__((ext_vector_type(8))) short bf16x8;
typedef __attribute__((ext_vector_type(4))) float f32x4;

__device__ inline unsigned short f2bf(float f) {  // RNE f32 -> bf16
    unsigned u = *(unsigned*)&f;
    u += 0x7fffu + ((u >> 16) & 1u);
    return (unsigned short)(u >> 16);
}
__device__ inline unsigned packbf(float a, float b) {
    return (unsigned)f2bf(a) | ((unsigned)f2bf(b) << 16);
}
__device__ inline void lds_fadd(float* p, float v) {
    __hip_atomic_fetch_add(p, v, __ATOMIC_RELAXED, __HIP_MEMORY_SCOPE_WORKGROUP);
}

__global__ __launch_bounds__(NT) void place_kernel(const int* __restrict__ src,
                                                   const int* __restrict__ dst,
                                                   int* __restrict__ cursor8,
                                                   unsigned* __restrict__ ebuf,
                                                   int E, int nbuk) {
    __shared__ int lh[MAXBUK];
    __shared__ int lbase[MAXBUK];
    for (int i = threadIdx.x; i < nbuk; i += NT) lh[i] = 0;
    __syncthreads();
    constexpr int EPT = EPB_B / NT;  // 16
    unsigned pk[EPT];
    unsigned bl[EPT];
    int base = blockIdx.x * EPB_B;
    int rep = blockIdx.x & (NREP - 1);
#pragma unroll
    for (int i = 0; i < EPT; i++) {
        int e = base + i * NT + threadIdx.x;
        if (e < E) {
            int s = src[e], d = dst[e];
            int b = d >> LOG_NPB;
            int lp = atomicAdd(&lh[b], 1);
            pk[i] = ((unsigned)(d & (NPB - 1)) << 24) | (unsigned)s;
            bl[i] = ((unsigned)b << 16) | (unsigned)lp;
        } else {
            bl[i] = 0xFFFFFFFFu;
        }
    }
    __syncthreads();
    for (int i = threadIdx.x; i < nbuk; i += NT) {
        int v = lh[i];
        if (v) lbase[i] = atomicAdd(&cursor8[rep * MAXBUK + i], v);
    }
    __syncthreads();
#pragma unroll
    for (int i = 0; i < EPT; i++) {
        if (bl[i] != 0xFFFFFFFFu) {
            int b = (int)(bl[i] >> 16);
            int pos = lbase[b] + (int)(bl[i] & 0xFFFFu);
            if (pos < SUB)
                ebuf[(size_t)b * BSTRIDE + rep * SUB + pos] = pk[i];
        }
    }
}

// Per-bucket in-degree count -> dinv. One coalesced pass over ebuf.
__global__ __launch_bounds__(NT) void degree_kernel(
    const unsigned* __restrict__ ebuf, const int* __restrict__ cursor8,
    float* __restrict__ dinv, int N) {
    __shared__ int cnt[NPB];
    int tid = threadIdx.x;
    int b = blockIdx.x;
    cnt[tid] = 0;
    __syncthreads();
#pragma unroll
    for (int r = 0; r < NREP; r++) {
        int e0 = b * BSTRIDE + r * SUB;
        int e1 = e0 + min(cursor8[r * MAXBUK + b], SUB);
        for (int i = e0 + tid; i < e1; i += NT)
            atomicAdd(&cnt[ebuf[i] >> 24], 1);
    }
    __syncthreads();
    int n = b * NPB + tid;
    if (n < N) dinv[n] = rsqrtf((float)cnt[tid] + 1.0f);
}

// Layer 1 GEMM 165->32 via MFMA 16x16x32 bf16. One wave per 16-node tile.
// Epilogue: dv scale -> bf16 pack -> hs[n][4]uint4 (32 contiguous bf16/node).
__global__ __launch_bounds__(NT) void gemm1_mfma(
    const float* __restrict__ in, const float* __restrict__ W,
    const float* __restrict__ dinv, uint4* __restrict__ hs, int Ntot) {
    constexpr int DIN = 165, DOUT = 32;
    __shared__ float tile[4][16][36];  // per-wave slices
    int lane = threadIdx.x & 63;
    int wv = threadIdx.x >> 6;
    int t = blockIdx.x * 4 + wv;
    int ntiles = (Ntot + 15) >> 4;
    if (t >= ntiles) return;
    int n0 = t << 4;
    int mrow = lane & 15;
    int quad = lane >> 4;
    int arow = n0 + mrow;
    if (arow >= Ntot) arow = Ntot - 1;  // clamp (read-only safety)
    const float* xrow = in + (size_t)arow * DIN;
    f32x4 acc0 = {0.f, 0.f, 0.f, 0.f};
    f32x4 acc1 = {0.f, 0.f, 0.f, 0.f};
#pragma unroll
    for (int c = 0; c < 6; c++) {
        int kb = c * 32 + quad * 8;
        union { bf16x8 v; unsigned short u[8]; } A, B0, B1;
#pragma unroll
        for (int j = 0; j < 8; j++) {
            int k = kb + j;
            float xv = (k < DIN) ? xrow[k] : 0.f;
            float w0 = (k < DIN) ? W[k * DOUT + mrow] : 0.f;
            float w1 = (k < DIN) ? W[k * DOUT + 16 + mrow] : 0.f;
            A.u[j] = f2bf(xv);
            B0.u[j] = f2bf(w0);
            B1.u[j] = f2bf(w1);
        }
        acc0 = __builtin_amdgcn_mfma_f32_16x16x32_bf16(A.v, B0.v, acc0, 0, 0, 0);
        acc1 = __builtin_amdgcn_mfma_f32_16x16x32_bf16(A.v, B1.v, acc1, 0, 0, 0);
    }
#pragma unroll
    for (int r = 0; r < 4; r++) {
        tile[wv][quad * 4 + r][mrow] = acc0[r];
        tile[wv][quad * 4 + r][16 + mrow] = acc1[r];
    }
    int node = lane >> 2;
    int part = lane & 3;          // features part*8 .. part*8+7
    int n = n0 + node;
    if (n >= Ntot) return;
    float dv = dinv[n];
    float f[8];
#pragma unroll
    for (int i = 0; i < 8; i++) f[i] = tile[wv][node][part * 8 + i];
    unsigned u0 = packbf(dv * f[0], dv * f[1]);
    unsigned u1 = packbf(dv * f[2], dv * f[3]);
    unsigned u2 = packbf(dv * f[4], dv * f[5]);
    unsigned u3 = packbf(dv * f[6], dv * f[7]);
    hs[(size_t)n * 4 + part] = make_uint4(u0, u1, u2, u3);
}

// Mid GEMMs: thread-per-node, float4 row loads; W/bias via uniform s_load.
// OUT==1 (DOUT=16): bf16-packed [N][2]uint4. OUT==0 (DOUT=2): f32.
template <int DIN, int DOUT, int OUT>
__global__ __launch_bounds__(NT) void gemm_kernel(
    const float* __restrict__ in, const float* __restrict__ bprev,
    const float* __restrict__ W, const float* __restrict__ dinv,
    void* __restrict__ hs, int N) {
    int n = blockIdx.x * NT + threadIdx.x;
    if (n >= N) return;
    float dv = dinv[n];
    float acc[DOUT];
#pragma unroll
    for (int d = 0; d < DOUT; d++) acc[d] = 0.f;
    const float4* row4 = (const float4*)(in + (size_t)n * DIN);
#pragma unroll
    for (int q = 0; q < DIN / 4; q++) {
        float4 v = row4[q];
        float xv[4] = {v.x, v.y, v.z, v.w};
#pragma unroll
        for (int j = 0; j < 4; j++) {
            int k = q * 4 + j;
            float f = fmaxf(fmaf(dv, xv[j], bprev[k]), 0.f);
#pragma unroll
            for (int d = 0; d < DOUT; d++)
                acc[d] = fmaf(f, W[k * DOUT + d], acc[d]);
        }
    }
    if constexpr (OUT == 1) {
        unsigned u[8];
#pragma unroll
        for (int i = 0; i < 8; i++)
            u[i] = packbf(dv * acc[2 * i], dv * acc[2 * i + 1]);
        uint4* hp = (uint4*)hs + (size_t)n * 2;
        hp[0] = make_uint4(u[0], u[1], u[2], u[3]);
        hp[1] = make_uint4(u[4], u[5], u[6], u[7]);
    } else {
        float2 h = {dv * acc[0], dv * acc[1]};
        *(float2*)((float*)hs + (size_t)n * 2) = h;
    }
}

// Edge-parallel scatter aggregation. One block per bucket; LDS acc[NF][256];
// streams the 8 packed subregions coalesced; ds_add_f32 per feature.
// Bank for acc[f][l] = l%32: random l over 64 lanes => ~2-way = free.
// Epilogue adds self-loop message (hsb[n]) and writes f32 [N][NF].
template <int NF>
__global__ __launch_bounds__(AT) void agg_kernel(
    const uint4* __restrict__ hsb, const unsigned* __restrict__ ebuf,
    const int* __restrict__ cursor8, float* __restrict__ aggOut, int N) {
    constexpr int NQ = NF / 8;
    __shared__ float acc[NF][NPB];
    int tid = threadIdx.x;
    int b = blockIdx.x;
    for (int i = tid; i < NF * NPB; i += AT) (&acc[0][0])[i] = 0.f;
    __syncthreads();
#pragma unroll
    for (int r = 0; r < NREP; r++) {
        int e0 = b * BSTRIDE + r * SUB;
        int e1 = e0 + min(cursor8[r * MAXBUK + b], SUB);
        for (int i = e0 + tid; i < e1; i += AT) {
            unsigned pk = ebuf[i];
            int l = (int)(pk >> 24);
            const uint4* hp = hsb + (size_t)(pk & 0xFFFFFFu) * NQ;
#pragma unroll
            for (int q = 0; q < NQ; q++) {
                uint4 v = hp[q];
                const unsigned* u = (const unsigned*)&v;
#pragma unroll
                for (int w = 0; w < 4; w++) {
                    unsigned lo = u[w] << 16, hi = u[w] & 0xffff0000u;
                    lds_fadd(&acc[q * 8 + 2 * w][l], *(float*)&lo);
                    lds_fadd(&acc[q * 8 + 2 * w + 1][l], *(float*)&hi);
                }
            }
        }
    }
    __syncthreads();
    for (int idx = tid; idx < NPB * NQ; idx += AT) {
        int l = idx / NQ, q = idx % NQ;
        int n = b * NPB + l;
        if (n >= N) continue;
        uint4 v = hsb[(size_t)n * NQ + q];  // self-loop message
        const unsigned* u = (const unsigned*)&v;
        float o[8];
#pragma unroll
        for (int w = 0; w < 4; w++) {
            unsigned lo = u[w] << 16, hi = u[w] & 0xffff0000u;
            o[2 * w]     = acc[q * 8 + 2 * w][l]     + *(float*)&lo;
            o[2 * w + 1] = acc[q * 8 + 2 * w + 1][l] + *(float*)&hi;
        }
        float4* ap = (float4*)(aggOut + (size_t)n * NF + q * 8);
        ap[0] = make_float4(o[0], o[1], o[2], o[3]);
        ap[1] = make_float4(o[4], o[5], o[6], o[7]);
    }
}

// Layer 3: scatter-agg of 2-feature messages + bias + log_softmax, fused.
__global__ __launch_bounds__(AT) void agg3_kernel(
    const float* __restrict__ hs3, const unsigned* __restrict__ ebuf,
    const int* __restrict__ cursor8, const float* __restrict__ dinv,
    const float* __restrict__ bias, float* __restrict__ out, int N) {
    __shared__ float acc0[NPB];
    __shared__ float acc1[NPB];
    int tid = threadIdx.x;
    int b = blockIdx.x;
    for (int i = tid; i < NPB; i += AT) { acc0[i] = 0.f; acc1[i] = 0.f; }
    __syncthreads();
#pragma unroll
    for (int r = 0; r < NREP; r++) {
        int e0 = b * BSTRIDE + r * SUB;
        int e1 = e0 + min(cursor8[r * MAXBUK + b], SUB);
        for (int i = e0 + tid; i < e1; i += AT) {
            unsigned pk = ebuf[i];
            int l = (int)(pk >> 24);
            float2 v = ((const float2*)hs3)[pk & 0xFFFFFFu];
            lds_fadd(&acc0[l], v.x);
            lds_fadd(&acc1[l], v.y);
        }
    }
    __syncthreads();
    for (int l = tid; l < NPB; l += AT) {
        int n = b * NPB + l;
        if (n >= N) continue;
        float2 self = ((const float2*)hs3)[n];
        float dv = dinv[n];
        float z0 = fmaf(dv, acc0[l] + self.x, bias[0]);
        float z1 = fmaf(dv, acc1[l] + self.y, bias[1]);
        float m = fmaxf(z0, z1);
        float lse = m + logf(expf(z0 - m) + expf(z1 - m));
        out[(size_t)n * 2 + 0] = z0 - lse;
        out[(size_t)n * 2 + 1] = z1 - lse;
    }
}

extern "C" void kernel_launch(void* const* d_in, const int* in_sizes, int n_in,
                              void* d_out, int out_size, void* d_ws, size_t ws_size,
                              hipStream_t stream) {
    const float* x  = (const float*)d_in[0];
    const int*   ei = (const int*)d_in[1];
    const float* W1 = (const float*)d_in[2];
    const float* b1 = (const float*)d_in[3];
    const float* W2 = (const float*)d_in[4];
    const float* b2 = (const float*)d_in[5];
    const float* W3 = (const float*)d_in[6];
    const float* b3 = (const float*)d_in[7];
    float* out = (float*)d_out;

    const int N = in_sizes[0] / 165;  // 100000
    const int E = in_sizes[1] / 2;    // 3200000
    const int* src = ei;
    const int* dst = ei + E;
    const int nbuk = (N + NPB - 1) >> LOG_NPB;  // 391
    const int NB = (N + NT - 1) / NT;           // 391

    char* p = (char*)d_ws;
    int* cursor8   = (int*)p;      p += (size_t)NREP * MAXBUK * 4;
    unsigned* ebuf = (unsigned*)p; p += (size_t)nbuk * BSTRIDE * 4;
    float* dinv    = (float*)p;    p += (size_t)N * 4;
    uint4* hs1b    = (uint4*)p;    p += (size_t)N * 4 * 16;  // bf16 [N][4]uint4
    float* agg1    = (float*)p;    p += (size_t)N * 32 * 4;  // f32 [N][32]
    uint4* hs2b    = (uint4*)p;    p += (size_t)N * 2 * 16;  // bf16 [N][2]uint4
    float* hs3     = (float*)p;    p += (size_t)N * 2 * 4;
    float* agg2    = (float*)hs1b;  // hs1b dead after agg1; f32 [N][16]

    hipMemsetAsync(cursor8, 0, (size_t)NREP * MAXBUK * sizeof(int), stream);
    place_kernel<<<(E + EPB_B - 1) / EPB_B, NT, 0, stream>>>(src, dst, cursor8, ebuf, E, nbuk);
    degree_kernel<<<nbuk, NT, 0, stream>>>(ebuf, cursor8, dinv, N);

    // Layer 1: 165 -> 32, MFMA, bf16 messages, scatter-agg
    gemm1_mfma<<<((N + 15) / 16 + 3) / 4, NT, 0, stream>>>(x, W1, dinv, hs1b, N);
    agg_kernel<32><<<nbuk, AT, 0, stream>>>(hs1b, ebuf, cursor8, agg1, N);

    // Layer 2: 32 -> 16, bf16 messages, scatter-agg
    gemm_kernel<32, 16, 1><<<NB, NT, 0, stream>>>(agg1, b1, W2, dinv, hs2b, N);
    agg_kernel<16><<<nbuk, AT, 0, stream>>>(hs2b, ebuf, cursor8, agg2, N);

    // Layer 3: 16 -> 2, scatter-agg + bias + log_softmax fused
    gemm_kernel<16, 2, 0><<<NB, NT, 0, stream>>>(agg2, b2, W3, dinv, hs3, N);
    agg3_kernel<<<nbuk, AT, 0, stream>>>(hs3, ebuf, cursor8, dinv, b3, out, N);
}

// Round 3
// 293.948 us; speedup vs baseline: 4.2287x; 4.2287x over previous
//
#include <hip/hip_runtime.h>
#include <math.h>

// ---------------------------------------------------------------------------
// GCN 165->32->16->2 + log_softmax, N=100k, E=3.2M.
//
// Round 13 (r12 + compile fix: cast hs3 to float2* at g2g3 call site):
//  - r11 POST-MORTEM: edge-parallel LDS-atomic scatter = 679us for layer 1
//    alone (102M lane atomics, VALUBusy 0.57%, 391-block grid). LDS atomic
//    RMW thrashes; CSR-gather wins by ~4x. Reverted.
//  - place/sort: r10 verbatim (8-way replicated cursors, in-LDS counting
//    sort -> esrc/rowptr/rowcnt/dinv).
//  - gemm1 epilogue writes [N][4]uint4: each node's 32 bf16 feats are ONE
//    64B line. Layer-1 gather: 2 lanes/node, lane pair reads the SAME line
//    (r10: 2 lines/edge + 2 dispatches + 2 esrc passes).
//  - g1g2: gather layer-1 + relu(dv*agg+b1) + 32->16 GEMM fused in-register
//    (2-lane shfl_xor exchange). Deletes agg1 roundtrip (25.6MB).
//  - g2g3: gather layer-2 + relu + 16->2 GEMM fused. Deletes agg2 roundtrip.
//  - Dispatches 9 -> 6.
// ---------------------------------------------------------------------------

constexpr int NT = 256;
constexpr int NPB = 256;       // nodes per bucket (partition)
constexpr int LOG_NPB = 8;
constexpr int MAXBUK = 512;
constexpr int BSTRIDE = 10240; // edge slots per bucket (mean 8184)
constexpr int NREP = 8;        // cursor replicas / subregions per bucket
constexpr int SUB = BSTRIDE / NREP;  // 1280 slots per subregion
constexpr int EPB_B = 4096;    // edges per block, place pass

typedef __attribute__((ext_vector_type(8))) short bf16x8;
typedef __attribute__((ext_vector_type(4))) float f32x4;

__device__ inline unsigned short f2bf(float f) {  // RNE f32 -> bf16
    unsigned u = *(unsigned*)&f;
    u += 0x7fffu + ((u >> 16) & 1u);
    return (unsigned short)(u >> 16);
}
__device__ inline unsigned packbf(float a, float b) {
    return (unsigned)f2bf(a) | ((unsigned)f2bf(b) << 16);
}
// accumulate 8 bf16 (one uint4) into a[0..7]
__device__ inline void acc8(float* a, uint4 v) {
    const unsigned* u = (const unsigned*)&v;
#pragma unroll
    for (int w = 0; w < 4; w++) {
        unsigned lo = u[w] << 16, hi = u[w] & 0xffff0000u;
        a[2 * w]     += *(float*)&lo;
        a[2 * w + 1] += *(float*)&hi;
    }
}

__global__ __launch_bounds__(NT) void place_kernel(const int* __restrict__ src,
                                                   const int* __restrict__ dst,
                                                   int* __restrict__ cursor8,
                                                   unsigned* __restrict__ ebuf,
                                                   int E, int nbuk) {
    __shared__ int lh[MAXBUK];
    __shared__ int lbase[MAXBUK];
    for (int i = threadIdx.x; i < nbuk; i += NT) lh[i] = 0;
    __syncthreads();
    constexpr int EPT = EPB_B / NT;  // 16
    unsigned pk[EPT];
    unsigned bl[EPT];
    int base = blockIdx.x * EPB_B;
    int rep = blockIdx.x & (NREP - 1);
#pragma unroll
    for (int i = 0; i < EPT; i++) {
        int e = base + i * NT + threadIdx.x;
        if (e < E) {
            int s = src[e], d = dst[e];
            int b = d >> LOG_NPB;
            int lp = atomicAdd(&lh[b], 1);
            pk[i] = ((unsigned)(d & (NPB - 1)) << 24) | (unsigned)s;
            bl[i] = ((unsigned)b << 16) | (unsigned)lp;
        } else {
            bl[i] = 0xFFFFFFFFu;
        }
    }
    __syncthreads();
    for (int i = threadIdx.x; i < nbuk; i += NT) {
        int v = lh[i];
        if (v) lbase[i] = atomicAdd(&cursor8[rep * MAXBUK + i], v);
    }
    __syncthreads();
#pragma unroll
    for (int i = 0; i < EPT; i++) {
        if (bl[i] != 0xFFFFFFFFu) {
            int b = (int)(bl[i] >> 16);
            int pos = lbase[b] + (int)(bl[i] & 0xFFFFu);
            if (pos < SUB)
                ebuf[(size_t)b * BSTRIDE + rep * SUB + pos] = pk[i];
        }
    }
}

// One block per bucket (256 nodes): in-LDS counting sort of (local<<24)|src
// from the 8 packed subregions into node-ordered esrc (bucket-strided);
// emits rowptr/rowcnt and dinv. Output range block-exclusive.
__global__ __launch_bounds__(NT) void sort_kernel(
    const unsigned* __restrict__ ebuf, const int* __restrict__ cursor8,
    int* __restrict__ esrc, int* __restrict__ rowptr, int* __restrict__ rowcnt,
    float* __restrict__ dinv, int N) {
    __shared__ int cnt[NPB];
    __shared__ int ofs[NPB];
    __shared__ int cur[NPB];
    int tid = threadIdx.x;
    int b = blockIdx.x;
    cnt[tid] = 0;
    __syncthreads();
#pragma unroll
    for (int r = 0; r < NREP; r++) {
        int e0 = b * BSTRIDE + r * SUB;
        int e1 = e0 + min(cursor8[r * MAXBUK + b], SUB);
        for (int i = e0 + tid; i < e1; i += NT)
            atomicAdd(&cnt[ebuf[i] >> 24], 1);
    }
    __syncthreads();
    ofs[tid] = cnt[tid];
    __syncthreads();
    for (int off = 1; off < NPB; off <<= 1) {
        int a = (tid >= off) ? ofs[tid - off] : 0;
        __syncthreads();
        ofs[tid] += a;
        __syncthreads();
    }
    {
        int excl = ofs[tid] - cnt[tid];
        cur[tid] = excl;
        int n = b * NPB + tid;
        if (n < N) {
            rowptr[n] = b * BSTRIDE + excl;
            rowcnt[n] = cnt[tid];
            dinv[n] = rsqrtf((float)cnt[tid] + 1.0f);
        }
    }
    __syncthreads();
#pragma unroll
    for (int r = 0; r < NREP; r++) {
        int e0 = b * BSTRIDE + r * SUB;
        int e1 = e0 + min(cursor8[r * MAXBUK + b], SUB);
        for (int i = e0 + tid; i < e1; i += NT) {
            unsigned p = ebuf[i];
            int l = (int)(p >> 24);
            int pos = atomicAdd(&cur[l], 1);
            esrc[b * BSTRIDE + pos] = (int)(p & 0xFFFFFFu);
        }
    }
}

// Layer 1 GEMM 165->32 via MFMA 16x16x32 bf16. One wave per 16-node tile.
// Epilogue: dv scale -> bf16 pack -> hs[n][4]uint4 (32 contiguous bf16/node,
// one 64B line per node so the gather's lane pair shares a line).
__global__ __launch_bounds__(NT) void gemm1_mfma(
    const float* __restrict__ in, const float* __restrict__ W,
    const float* __restrict__ dinv, uint4* __restrict__ hs, int Ntot) {
    constexpr int DIN = 165, DOUT = 32;
    __shared__ float tile[4][16][36];  // per-wave slices
    int lane = threadIdx.x & 63;
    int wv = threadIdx.x >> 6;
    int t = blockIdx.x * 4 + wv;
    int ntiles = (Ntot + 15) >> 4;
    if (t >= ntiles) return;
    int n0 = t << 4;
    int mrow = lane & 15;
    int quad = lane >> 4;
    int arow = n0 + mrow;
    if (arow >= Ntot) arow = Ntot - 1;  // clamp (read-only safety)
    const float* xrow = in + (size_t)arow * DIN;
    f32x4 acc0 = {0.f, 0.f, 0.f, 0.f};
    f32x4 acc1 = {0.f, 0.f, 0.f, 0.f};
#pragma unroll
    for (int c = 0; c < 6; c++) {
        int kb = c * 32 + quad * 8;
        union { bf16x8 v; unsigned short u[8]; } A, B0, B1;
#pragma unroll
        for (int j = 0; j < 8; j++) {
            int k = kb + j;
            float xv = (k < DIN) ? xrow[k] : 0.f;
            float w0 = (k < DIN) ? W[k * DOUT + mrow] : 0.f;
            float w1 = (k < DIN) ? W[k * DOUT + 16 + mrow] : 0.f;
            A.u[j] = f2bf(xv);
            B0.u[j] = f2bf(w0);
            B1.u[j] = f2bf(w1);
        }
        acc0 = __builtin_amdgcn_mfma_f32_16x16x32_bf16(A.v, B0.v, acc0, 0, 0, 0);
        acc1 = __builtin_amdgcn_mfma_f32_16x16x32_bf16(A.v, B1.v, acc1, 0, 0, 0);
    }
#pragma unroll
    for (int r = 0; r < 4; r++) {
        tile[wv][quad * 4 + r][mrow] = acc0[r];
        tile[wv][quad * 4 + r][16 + mrow] = acc1[r];
    }
    int node = lane >> 2;
    int part = lane & 3;          // features part*8 .. part*8+7
    int n = n0 + node;
    if (n >= Ntot) return;
    float dv = dinv[n];
    float f[8];
#pragma unroll
    for (int i = 0; i < 8; i++) f[i] = tile[wv][node][part * 8 + i];
    unsigned u0 = packbf(dv * f[0], dv * f[1]);
    unsigned u1 = packbf(dv * f[2], dv * f[3]);
    unsigned u2 = packbf(dv * f[4], dv * f[5]);
    unsigned u3 = packbf(dv * f[6], dv * f[7]);
    hs[(size_t)n * 4 + part] = make_uint4(u0, u1, u2, u3);
}

// Fused layer-1 gather + relu(dv*agg+b1) + 32->16 GEMM + bf16 message pack.
// 2 lanes per node; lane c owns feats c*16..c*16+15 (2 adjacent uint4 = 32B;
// the pair covers one 64B line). Cross-lane via shfl_xor(.,1).
__global__ __launch_bounds__(NT) void g1g2_kernel(
    const uint4* __restrict__ hsb, const int* __restrict__ esrc,
    const int* __restrict__ rowptr, const int* __restrict__ rowcnt,
    const float* __restrict__ dinv, const float* __restrict__ b1,
    const float* __restrict__ W2 /*[32][16]*/, uint4* __restrict__ hs2b,
    int N) {
    __shared__ float sW[32 * 16];
    __shared__ float sb[32];
    for (int i = threadIdx.x; i < 32 * 16; i += NT) sW[i] = W2[i];
    if (threadIdx.x < 32) sb[threadIdx.x] = b1[threadIdx.x];
    __syncthreads();
    int gid = blockIdx.x * NT + threadIdx.x;
    int n = gid >> 1;
    int c = gid & 1;
    if (n >= N) return;
    int j = rowptr[n];
    int end = j + rowcnt[n];
    float a[16];
    {   // self-loop message
        const uint4* hp = hsb + (size_t)n * 4 + c * 2;
        uint4 v0 = hp[0], v1 = hp[1];
        const unsigned* u0 = (const unsigned*)&v0;
        const unsigned* u1 = (const unsigned*)&v1;
#pragma unroll
        for (int w = 0; w < 4; w++) {
            unsigned lo = u0[w] << 16, hi = u0[w] & 0xffff0000u;
            a[2 * w] = *(float*)&lo; a[2 * w + 1] = *(float*)&hi;
            unsigned lo1 = u1[w] << 16, hi1 = u1[w] & 0xffff0000u;
            a[8 + 2 * w] = *(float*)&lo1; a[8 + 2 * w + 1] = *(float*)&hi1;
        }
    }
    for (; j + 4 <= end; j += 4) {
        int s0 = esrc[j], s1 = esrc[j + 1], s2 = esrc[j + 2], s3 = esrc[j + 3];
        uint4 v00 = hsb[(size_t)s0 * 4 + c * 2], v01 = hsb[(size_t)s0 * 4 + c * 2 + 1];
        uint4 v10 = hsb[(size_t)s1 * 4 + c * 2], v11 = hsb[(size_t)s1 * 4 + c * 2 + 1];
        uint4 v20 = hsb[(size_t)s2 * 4 + c * 2], v21 = hsb[(size_t)s2 * 4 + c * 2 + 1];
        uint4 v30 = hsb[(size_t)s3 * 4 + c * 2], v31 = hsb[(size_t)s3 * 4 + c * 2 + 1];
        acc8(a, v00); acc8(a + 8, v01);
        acc8(a, v10); acc8(a + 8, v11);
        acc8(a, v20); acc8(a + 8, v21);
        acc8(a, v30); acc8(a + 8, v31);
    }
    for (; j < end; j++) {
        int s = esrc[j];
        acc8(a, hsb[(size_t)s * 4 + c * 2]);
        acc8(a + 8, hsb[(size_t)s * 4 + c * 2 + 1]);
    }
    float dv = dinv[n];
    float z[16];
#pragma unroll
    for (int d = 0; d < 16; d++) z[d] = 0.f;
#pragma unroll
    for (int k = 0; k < 16; k++) {
        float f = fmaxf(fmaf(dv, a[k], sb[c * 16 + k]), 0.f);
#pragma unroll
        for (int d = 0; d < 16; d++)
            z[d] = fmaf(f, sW[(c * 16 + k) * 16 + d], z[d]);
    }
#pragma unroll
    for (int d = 0; d < 16; d++) z[d] += __shfl_xor(z[d], 1);
    // lane c packs outputs c*8 .. c*8+7 (message = dv * acc)
    unsigned u0 = packbf(dv * z[c * 8 + 0], dv * z[c * 8 + 1]);
    unsigned u1 = packbf(dv * z[c * 8 + 2], dv * z[c * 8 + 3]);
    unsigned u2 = packbf(dv * z[c * 8 + 4], dv * z[c * 8 + 5]);
    unsigned u3 = packbf(dv * z[c * 8 + 6], dv * z[c * 8 + 7]);
    hs2b[(size_t)n * 2 + c] = make_uint4(u0, u1, u2, u3);
}

// Fused layer-2 gather + relu(dv*agg+b2) + 16->2 GEMM -> hs3 (f32 [N][2]).
// 2 lanes per node; lane c owns feats c*8..c*8+7 (one uint4, pair = 32B).
__global__ __launch_bounds__(NT) void g2g3_kernel(
    const uint4* __restrict__ hs2b, const int* __restrict__ esrc,
    const int* __restrict__ rowptr, const int* __restrict__ rowcnt,
    const float* __restrict__ dinv, const float* __restrict__ b2,
    const float* __restrict__ W3 /*[16][2]*/, float* __restrict__ hs3,
    int N) {
    __shared__ float sW[32];
    __shared__ float sb[16];
    if (threadIdx.x < 32) sW[threadIdx.x] = W3[threadIdx.x];
    if (threadIdx.x < 16) sb[threadIdx.x] = b2[threadIdx.x];
    __syncthreads();
    int gid = blockIdx.x * NT + threadIdx.x;
    int n = gid >> 1;
    int c = gid & 1;
    if (n >= N) return;
    int j = rowptr[n];
    int end = j + rowcnt[n];
    float a[8];
    {   // self-loop message
        uint4 v = hs2b[(size_t)n * 2 + c];
        const unsigned* u = (const unsigned*)&v;
#pragma unroll
        for (int w = 0; w < 4; w++) {
            unsigned lo = u[w] << 16, hi = u[w] & 0xffff0000u;
            a[2 * w] = *(float*)&lo; a[2 * w + 1] = *(float*)&hi;
        }
    }
    for (; j + 4 <= end; j += 4) {
        uint4 v0 = hs2b[(size_t)esrc[j] * 2 + c];
        uint4 v1 = hs2b[(size_t)esrc[j + 1] * 2 + c];
        uint4 v2 = hs2b[(size_t)esrc[j + 2] * 2 + c];
        uint4 v3 = hs2b[(size_t)esrc[j + 3] * 2 + c];
        acc8(a, v0); acc8(a, v1); acc8(a, v2); acc8(a, v3);
    }
    for (; j < end; j++) acc8(a, hs2b[(size_t)esrc[j] * 2 + c]);
    float dv = dinv[n];
    float z0 = 0.f, z1 = 0.f;
#pragma unroll
    for (int k = 0; k < 8; k++) {
        float f = fmaxf(fmaf(dv, a[k], sb[c * 8 + k]), 0.f);
        z0 = fmaf(f, sW[(c * 8 + k) * 2 + 0], z0);
        z1 = fmaf(f, sW[(c * 8 + k) * 2 + 1], z1);
    }
    z0 += __shfl_xor(z0, 1);
    z1 += __shfl_xor(z1, 1);
    if (c == 0) {
        hs3[(size_t)n * 2 + 0] = dv * z0;
        hs3[(size_t)n * 2 + 1] = dv * z1;
    }
}

// Layer 3 gather (hs3 0.8MB, L2-resident) + bias + log_softmax.
__global__ __launch_bounds__(NT) void final_kernel(
    const float* __restrict__ hs3, const int* __restrict__ esrc,
    const int* __restrict__ rowptr, const int* __restrict__ rowcnt,
    const float* __restrict__ dinv, const float* __restrict__ b,
    float* __restrict__ out, int N) {
    int n = blockIdx.x * NT + threadIdx.x;
    if (n >= N) return;
    int j = rowptr[n];
    int end = j + rowcnt[n];
    const float2* h2 = (const float2*)hs3;
    float2 acc = h2[n];
    for (; j + 4 <= end; j += 4) {
        float2 v0 = h2[esrc[j]], v1 = h2[esrc[j + 1]];
        float2 v2 = h2[esrc[j + 2]], v3 = h2[esrc[j + 3]];
        acc.x += v0.x + v1.x + v2.x + v3.x;
        acc.y += v0.y + v1.y + v2.y + v3.y;
    }
    for (; j < end; j++) {
        float2 v = h2[esrc[j]];
        acc.x += v.x; acc.y += v.y;
    }
    float dv = dinv[n];
    float z0 = fmaf(dv, acc.x, b[0]);
    float z1 = fmaf(dv, acc.y, b[1]);
    float m = fmaxf(z0, z1);
    float lse = m + logf(expf(z0 - m) + expf(z1 - m));
    out[(size_t)n * 2 + 0] = z0 - lse;
    out[(size_t)n * 2 + 1] = z1 - lse;
}

extern "C" void kernel_launch(void* const* d_in, const int* in_sizes, int n_in,
                              void* d_out, int out_size, void* d_ws, size_t ws_size,
                              hipStream_t stream) {
    const float* x  = (const float*)d_in[0];
    const int*   ei = (const int*)d_in[1];
    const float* W1 = (const float*)d_in[2];
    const float* b1 = (const float*)d_in[3];
    const float* W2 = (const float*)d_in[4];
    const float* b2 = (const float*)d_in[5];
    const float* W3 = (const float*)d_in[6];
    const float* b3 = (const float*)d_in[7];
    float* out = (float*)d_out;

    const int N = in_sizes[0] / 165;  // 100000
    const int E = in_sizes[1] / 2;    // 3200000
    const int* src = ei;
    const int* dst = ei + E;
    const int nbuk = (N + NPB - 1) >> LOG_NPB;  // 391
    const int NB = (N + NT - 1) / NT;           // 391
    const int GB = ((size_t)N * 2 + NT - 1) / NT;  // 2 lanes/node dispatches

    char* p = (char*)d_ws;
    int* cursor8   = (int*)p;      p += (size_t)NREP * MAXBUK * 4;
    unsigned* ebuf = (unsigned*)p; p += (size_t)nbuk * BSTRIDE * 4;
    int* esrc      = (int*)p;      p += (size_t)nbuk * BSTRIDE * 4;
    int* rowptr    = (int*)p;      p += (size_t)N * 4;
    int* rowcnt    = (int*)p;      p += (size_t)N * 4;
    float* dinv    = (float*)p;    p += (size_t)N * 4;
    uint4* hs1b    = (uint4*)p;    p += (size_t)N * 4 * 16;  // bf16 [N][4]uint4
    uint4* hs2b    = (uint4*)p;    p += (size_t)N * 2 * 16;  // bf16 [N][2]uint4
    float* hs3     = (float*)p;    p += (size_t)N * 2 * 4;   // f32 [N][2]

    (void)hipMemsetAsync(cursor8, 0, (size_t)NREP * MAXBUK * sizeof(int), stream);
    place_kernel<<<(E + EPB_B - 1) / EPB_B, NT, 0, stream>>>(src, dst, cursor8, ebuf, E, nbuk);
    sort_kernel<<<nbuk, NT, 0, stream>>>(ebuf, cursor8, esrc, rowptr, rowcnt, dinv, N);

    // Layer 1: 165 -> 32 MFMA, bf16 messages (one 64B line per node)
    gemm1_mfma<<<((N + 15) / 16 + 3) / 4, NT, 0, stream>>>(x, W1, dinv, hs1b, N);

    // Layer 1 gather + layer 2 GEMM fused
    g1g2_kernel<<<GB, NT, 0, stream>>>(hs1b, esrc, rowptr, rowcnt, dinv, b1, W2, hs2b, N);

    // Layer 2 gather + layer 3 GEMM fused
    g2g3_kernel<<<GB, NT, 0, stream>>>(hs2b, esrc, rowptr, rowcnt, dinv, b2, W3, hs3, N);

    // Layer 3 gather + bias + log_softmax
    final_kernel<<<NB, NT, 0, stream>>>(hs3, esrc, rowptr, rowcnt, dinv, b3, out, N);
}

// Round 4
// 279.638 us; speedup vs baseline: 4.4451x; 1.0512x over previous
//
#include <hip/hip_runtime.h>
#include <math.h>

// ---------------------------------------------------------------------------
// GCN 165->32->16->2 + log_softmax, N=100k, E=3.2M.
//
// Round 14 (r13 + gather concurrency):
//  - r13 POST-MORTEM: g1g2 56us, Occupancy 26% (work-limited: 200k threads),
//    VALUBusy 15%, FETCH 142MB@2.5TB/s fill -> latency/in-flight bound.
//  - g1g2/g2g3: 4 lanes/node = 2 feature-halves (c) x 2 contiguous
//    edge-halves (h). Serial chain halved, waves/CU doubled (~24). Edge
//    halves combine via shfl_xor(a,2) BEFORE relu; feature halves combine
//    GEMM partials via shfl_xor(z,1). Line traffic unchanged (c-pair still
//    shares one 64B line).
//  - final: 2 lanes/node edge-split, shfl_xor(.,1) combine.
//  - place/sort/gemm1: r13 verbatim.
// ---------------------------------------------------------------------------

constexpr int NT = 256;
constexpr int NPB = 256;       // nodes per bucket (partition)
constexpr int LOG_NPB = 8;
constexpr int MAXBUK = 512;
constexpr int BSTRIDE = 10240; // edge slots per bucket (mean 8184)
constexpr int NREP = 8;        // cursor replicas / subregions per bucket
constexpr int SUB = BSTRIDE / NREP;  // 1280 slots per subregion
constexpr int EPB_B = 4096;    // edges per block, place pass

typedef __attribute__((ext_vector_type(8))) short bf16x8;
typedef __attribute__((ext_vector_type(4))) float f32x4;

__device__ inline unsigned short f2bf(float f) {  // RNE f32 -> bf16
    unsigned u = *(unsigned*)&f;
    u += 0x7fffu + ((u >> 16) & 1u);
    return (unsigned short)(u >> 16);
}
__device__ inline unsigned packbf(float a, float b) {
    return (unsigned)f2bf(a) | ((unsigned)f2bf(b) << 16);
}
// accumulate 8 bf16 (one uint4) into a[0..7]
__device__ inline void acc8(float* a, uint4 v) {
    const unsigned* u = (const unsigned*)&v;
#pragma unroll
    for (int w = 0; w < 4; w++) {
        unsigned lo = u[w] << 16, hi = u[w] & 0xffff0000u;
        a[2 * w]     += *(float*)&lo;
        a[2 * w + 1] += *(float*)&hi;
    }
}

__global__ __launch_bounds__(NT) void place_kernel(const int* __restrict__ src,
                                                   const int* __restrict__ dst,
                                                   int* __restrict__ cursor8,
                                                   unsigned* __restrict__ ebuf,
                                                   int E, int nbuk) {
    __shared__ int lh[MAXBUK];
    __shared__ int lbase[MAXBUK];
    for (int i = threadIdx.x; i < nbuk; i += NT) lh[i] = 0;
    __syncthreads();
    constexpr int EPT = EPB_B / NT;  // 16
    unsigned pk[EPT];
    unsigned bl[EPT];
    int base = blockIdx.x * EPB_B;
    int rep = blockIdx.x & (NREP - 1);
#pragma unroll
    for (int i = 0; i < EPT; i++) {
        int e = base + i * NT + threadIdx.x;
        if (e < E) {
            int s = src[e], d = dst[e];
            int b = d >> LOG_NPB;
            int lp = atomicAdd(&lh[b], 1);
            pk[i] = ((unsigned)(d & (NPB - 1)) << 24) | (unsigned)s;
            bl[i] = ((unsigned)b << 16) | (unsigned)lp;
        } else {
            bl[i] = 0xFFFFFFFFu;
        }
    }
    __syncthreads();
    for (int i = threadIdx.x; i < nbuk; i += NT) {
        int v = lh[i];
        if (v) lbase[i] = atomicAdd(&cursor8[rep * MAXBUK + i], v);
    }
    __syncthreads();
#pragma unroll
    for (int i = 0; i < EPT; i++) {
        if (bl[i] != 0xFFFFFFFFu) {
            int b = (int)(bl[i] >> 16);
            int pos = lbase[b] + (int)(bl[i] & 0xFFFFu);
            if (pos < SUB)
                ebuf[(size_t)b * BSTRIDE + rep * SUB + pos] = pk[i];
        }
    }
}

// One block per bucket (256 nodes): in-LDS counting sort of (local<<24)|src
// from the 8 packed subregions into node-ordered esrc (bucket-strided);
// emits rowptr/rowcnt and dinv. Output range block-exclusive.
__global__ __launch_bounds__(NT) void sort_kernel(
    const unsigned* __restrict__ ebuf, const int* __restrict__ cursor8,
    int* __restrict__ esrc, int* __restrict__ rowptr, int* __restrict__ rowcnt,
    float* __restrict__ dinv, int N) {
    __shared__ int cnt[NPB];
    __shared__ int ofs[NPB];
    __shared__ int cur[NPB];
    int tid = threadIdx.x;
    int b = blockIdx.x;
    cnt[tid] = 0;
    __syncthreads();
#pragma unroll
    for (int r = 0; r < NREP; r++) {
        int e0 = b * BSTRIDE + r * SUB;
        int e1 = e0 + min(cursor8[r * MAXBUK + b], SUB);
        for (int i = e0 + tid; i < e1; i += NT)
            atomicAdd(&cnt[ebuf[i] >> 24], 1);
    }
    __syncthreads();
    ofs[tid] = cnt[tid];
    __syncthreads();
    for (int off = 1; off < NPB; off <<= 1) {
        int a = (tid >= off) ? ofs[tid - off] : 0;
        __syncthreads();
        ofs[tid] += a;
        __syncthreads();
    }
    {
        int excl = ofs[tid] - cnt[tid];
        cur[tid] = excl;
        int n = b * NPB + tid;
        if (n < N) {
            rowptr[n] = b * BSTRIDE + excl;
            rowcnt[n] = cnt[tid];
            dinv[n] = rsqrtf((float)cnt[tid] + 1.0f);
        }
    }
    __syncthreads();
#pragma unroll
    for (int r = 0; r < NREP; r++) {
        int e0 = b * BSTRIDE + r * SUB;
        int e1 = e0 + min(cursor8[r * MAXBUK + b], SUB);
        for (int i = e0 + tid; i < e1; i += NT) {
            unsigned p = ebuf[i];
            int l = (int)(p >> 24);
            int pos = atomicAdd(&cur[l], 1);
            esrc[b * BSTRIDE + pos] = (int)(p & 0xFFFFFFu);
        }
    }
}

// Layer 1 GEMM 165->32 via MFMA 16x16x32 bf16. One wave per 16-node tile.
// Epilogue: dv scale -> bf16 pack -> hs[n][4]uint4 (32 contiguous bf16/node,
// one 64B line per node so the gather's lane group shares a line).
__global__ __launch_bounds__(NT) void gemm1_mfma(
    const float* __restrict__ in, const float* __restrict__ W,
    const float* __restrict__ dinv, uint4* __restrict__ hs, int Ntot) {
    constexpr int DIN = 165, DOUT = 32;
    __shared__ float tile[4][16][36];  // per-wave slices
    int lane = threadIdx.x & 63;
    int wv = threadIdx.x >> 6;
    int t = blockIdx.x * 4 + wv;
    int ntiles = (Ntot + 15) >> 4;
    if (t >= ntiles) return;
    int n0 = t << 4;
    int mrow = lane & 15;
    int quad = lane >> 4;
    int arow = n0 + mrow;
    if (arow >= Ntot) arow = Ntot - 1;  // clamp (read-only safety)
    const float* xrow = in + (size_t)arow * DIN;
    f32x4 acc0 = {0.f, 0.f, 0.f, 0.f};
    f32x4 acc1 = {0.f, 0.f, 0.f, 0.f};
#pragma unroll
    for (int c = 0; c < 6; c++) {
        int kb = c * 32 + quad * 8;
        union { bf16x8 v; unsigned short u[8]; } A, B0, B1;
#pragma unroll
        for (int j = 0; j < 8; j++) {
            int k = kb + j;
            float xv = (k < DIN) ? xrow[k] : 0.f;
            float w0 = (k < DIN) ? W[k * DOUT + mrow] : 0.f;
            float w1 = (k < DIN) ? W[k * DOUT + 16 + mrow] : 0.f;
            A.u[j] = f2bf(xv);
            B0.u[j] = f2bf(w0);
            B1.u[j] = f2bf(w1);
        }
        acc0 = __builtin_amdgcn_mfma_f32_16x16x32_bf16(A.v, B0.v, acc0, 0, 0, 0);
        acc1 = __builtin_amdgcn_mfma_f32_16x16x32_bf16(A.v, B1.v, acc1, 0, 0, 0);
    }
#pragma unroll
    for (int r = 0; r < 4; r++) {
        tile[wv][quad * 4 + r][mrow] = acc0[r];
        tile[wv][quad * 4 + r][16 + mrow] = acc1[r];
    }
    int node = lane >> 2;
    int part = lane & 3;          // features part*8 .. part*8+7
    int n = n0 + node;
    if (n >= Ntot) return;
    float dv = dinv[n];
    float f[8];
#pragma unroll
    for (int i = 0; i < 8; i++) f[i] = tile[wv][node][part * 8 + i];
    unsigned u0 = packbf(dv * f[0], dv * f[1]);
    unsigned u1 = packbf(dv * f[2], dv * f[3]);
    unsigned u2 = packbf(dv * f[4], dv * f[5]);
    unsigned u3 = packbf(dv * f[6], dv * f[7]);
    hs[(size_t)n * 4 + part] = make_uint4(u0, u1, u2, u3);
}

// Fused layer-1 gather + relu(dv*agg+b1) + 32->16 GEMM + bf16 message pack.
// 4 lanes/node: c = feature half (feats c*16..+15, 2 uint4 = 32B), h = edge
// half (contiguous split). The two c-lanes of a half share each 64B line.
// Edge halves combine via shfl_xor(a,2) BEFORE relu; feature-half GEMM
// partials combine via shfl_xor(z,1).
__global__ __launch_bounds__(NT) void g1g2_kernel(
    const uint4* __restrict__ hsb, const int* __restrict__ esrc,
    const int* __restrict__ rowptr, const int* __restrict__ rowcnt,
    const float* __restrict__ dinv, const float* __restrict__ b1,
    const float* __restrict__ W2 /*[32][16]*/, uint4* __restrict__ hs2b,
    int N) {
    __shared__ float sW[32 * 16];
    __shared__ float sb[32];
    for (int i = threadIdx.x; i < 32 * 16; i += NT) sW[i] = W2[i];
    if (threadIdx.x < 32) sb[threadIdx.x] = b1[threadIdx.x];
    __syncthreads();
    int gid = blockIdx.x * NT + threadIdx.x;
    int n = gid >> 2;
    int q = gid & 3;
    int c = q & 1;
    int h = q >> 1;
    if (n >= N) return;
    int start = rowptr[n];
    int cnt = rowcnt[n];
    int half0 = (cnt + 1) >> 1;
    int j    = start + (h ? half0 : 0);
    int jend = start + (h ? cnt : half0);
    float a[16];
    if (h == 0) {  // self-loop message
        const uint4* hp = hsb + (size_t)n * 4 + c * 2;
        uint4 v0 = hp[0], v1 = hp[1];
        const unsigned* u0 = (const unsigned*)&v0;
        const unsigned* u1 = (const unsigned*)&v1;
#pragma unroll
        for (int w = 0; w < 4; w++) {
            unsigned lo = u0[w] << 16, hi = u0[w] & 0xffff0000u;
            a[2 * w] = *(float*)&lo; a[2 * w + 1] = *(float*)&hi;
            unsigned lo1 = u1[w] << 16, hi1 = u1[w] & 0xffff0000u;
            a[8 + 2 * w] = *(float*)&lo1; a[8 + 2 * w + 1] = *(float*)&hi1;
        }
    } else {
#pragma unroll
        for (int k = 0; k < 16; k++) a[k] = 0.f;
    }
    for (; j + 3 < jend; j += 4) {
        int s0 = esrc[j], s1 = esrc[j + 1], s2 = esrc[j + 2], s3 = esrc[j + 3];
        uint4 v00 = hsb[(size_t)s0 * 4 + c * 2], v01 = hsb[(size_t)s0 * 4 + c * 2 + 1];
        uint4 v10 = hsb[(size_t)s1 * 4 + c * 2], v11 = hsb[(size_t)s1 * 4 + c * 2 + 1];
        uint4 v20 = hsb[(size_t)s2 * 4 + c * 2], v21 = hsb[(size_t)s2 * 4 + c * 2 + 1];
        uint4 v30 = hsb[(size_t)s3 * 4 + c * 2], v31 = hsb[(size_t)s3 * 4 + c * 2 + 1];
        acc8(a, v00); acc8(a + 8, v01);
        acc8(a, v10); acc8(a + 8, v11);
        acc8(a, v20); acc8(a + 8, v21);
        acc8(a, v30); acc8(a + 8, v31);
    }
    for (; j < jend; j++) {
        int s = esrc[j];
        acc8(a, hsb[(size_t)s * 4 + c * 2]);
        acc8(a + 8, hsb[(size_t)s * 4 + c * 2 + 1]);
    }
    // combine edge halves (lane +-2): full aggregation before relu
#pragma unroll
    for (int k = 0; k < 16; k++) a[k] += __shfl_xor(a[k], 2);
    float dv = dinv[n];
    float z[16];
#pragma unroll
    for (int d = 0; d < 16; d++) z[d] = 0.f;
#pragma unroll
    for (int k = 0; k < 16; k++) {
        float f = fmaxf(fmaf(dv, a[k], sb[c * 16 + k]), 0.f);
#pragma unroll
        for (int d = 0; d < 16; d++)
            z[d] = fmaf(f, sW[(c * 16 + k) * 16 + d], z[d]);
    }
    // combine feature halves (lane +-1): full z on all 4 lanes
#pragma unroll
    for (int d = 0; d < 16; d++) z[d] += __shfl_xor(z[d], 1);
    if (h == 0) {  // lane c packs outputs c*8 .. c*8+7 (message = dv * z)
        unsigned u0 = packbf(dv * z[c * 8 + 0], dv * z[c * 8 + 1]);
        unsigned u1 = packbf(dv * z[c * 8 + 2], dv * z[c * 8 + 3]);
        unsigned u2 = packbf(dv * z[c * 8 + 4], dv * z[c * 8 + 5]);
        unsigned u3 = packbf(dv * z[c * 8 + 6], dv * z[c * 8 + 7]);
        hs2b[(size_t)n * 2 + c] = make_uint4(u0, u1, u2, u3);
    }
}

// Fused layer-2 gather + relu(dv*agg+b2) + 16->2 GEMM -> hs3 (f32 [N][2]).
// 4 lanes/node: c = feature half (one uint4, 16B; c-pair shares 32B),
// h = edge half. Combine pattern as g1g2.
__global__ __launch_bounds__(NT) void g2g3_kernel(
    const uint4* __restrict__ hs2b, const int* __restrict__ esrc,
    const int* __restrict__ rowptr, const int* __restrict__ rowcnt,
    const float* __restrict__ dinv, const float* __restrict__ b2,
    const float* __restrict__ W3 /*[16][2]*/, float* __restrict__ hs3,
    int N) {
    __shared__ float sW[32];
    __shared__ float sb[16];
    if (threadIdx.x < 32) sW[threadIdx.x] = W3[threadIdx.x];
    if (threadIdx.x < 16) sb[threadIdx.x] = b2[threadIdx.x];
    __syncthreads();
    int gid = blockIdx.x * NT + threadIdx.x;
    int n = gid >> 2;
    int q = gid & 3;
    int c = q & 1;
    int h = q >> 1;
    if (n >= N) return;
    int start = rowptr[n];
    int cnt = rowcnt[n];
    int half0 = (cnt + 1) >> 1;
    int j    = start + (h ? half0 : 0);
    int jend = start + (h ? cnt : half0);
    float a[8];
    if (h == 0) {  // self-loop message
        uint4 v = hs2b[(size_t)n * 2 + c];
        const unsigned* u = (const unsigned*)&v;
#pragma unroll
        for (int w = 0; w < 4; w++) {
            unsigned lo = u[w] << 16, hi = u[w] & 0xffff0000u;
            a[2 * w] = *(float*)&lo; a[2 * w + 1] = *(float*)&hi;
        }
    } else {
#pragma unroll
        for (int k = 0; k < 8; k++) a[k] = 0.f;
    }
    for (; j + 3 < jend; j += 4) {
        uint4 v0 = hs2b[(size_t)esrc[j] * 2 + c];
        uint4 v1 = hs2b[(size_t)esrc[j + 1] * 2 + c];
        uint4 v2 = hs2b[(size_t)esrc[j + 2] * 2 + c];
        uint4 v3 = hs2b[(size_t)esrc[j + 3] * 2 + c];
        acc8(a, v0); acc8(a, v1); acc8(a, v2); acc8(a, v3);
    }
    for (; j < jend; j++) acc8(a, hs2b[(size_t)esrc[j] * 2 + c]);
    // combine edge halves before relu
#pragma unroll
    for (int k = 0; k < 8; k++) a[k] += __shfl_xor(a[k], 2);
    float dv = dinv[n];
    float z0 = 0.f, z1 = 0.f;
#pragma unroll
    for (int k = 0; k < 8; k++) {
        float f = fmaxf(fmaf(dv, a[k], sb[c * 8 + k]), 0.f);
        z0 = fmaf(f, sW[(c * 8 + k) * 2 + 0], z0);
        z1 = fmaf(f, sW[(c * 8 + k) * 2 + 1], z1);
    }
    z0 += __shfl_xor(z0, 1);
    z1 += __shfl_xor(z1, 1);
    if (q == 0) {
        hs3[(size_t)n * 2 + 0] = dv * z0;
        hs3[(size_t)n * 2 + 1] = dv * z1;
    }
}

// Layer 3 gather (hs3 0.8MB, L2-resident) + bias + log_softmax.
// 2 lanes/node, contiguous edge halves, shfl_xor(1) combine.
__global__ __launch_bounds__(NT) void final_kernel(
    const float* __restrict__ hs3, const int* __restrict__ esrc,
    const int* __restrict__ rowptr, const int* __restrict__ rowcnt,
    const float* __restrict__ dinv, const float* __restrict__ b,
    float* __restrict__ out, int N) {
    int gid = blockIdx.x * NT + threadIdx.x;
    int n = gid >> 1;
    int h = gid & 1;
    if (n >= N) return;
    int start = rowptr[n];
    int cnt = rowcnt[n];
    int half0 = (cnt + 1) >> 1;
    int j    = start + (h ? half0 : 0);
    int jend = start + (h ? cnt : half0);
    const float2* h2 = (const float2*)hs3;
    float2 acc = h ? make_float2(0.f, 0.f) : h2[n];  // self-loop on h=0
    for (; j + 3 < jend; j += 4) {
        float2 v0 = h2[esrc[j]], v1 = h2[esrc[j + 1]];
        float2 v2 = h2[esrc[j + 2]], v3 = h2[esrc[j + 3]];
        acc.x += v0.x + v1.x + v2.x + v3.x;
        acc.y += v0.y + v1.y + v2.y + v3.y;
    }
    for (; j < jend; j++) {
        float2 v = h2[esrc[j]];
        acc.x += v.x; acc.y += v.y;
    }
    acc.x += __shfl_xor(acc.x, 1);
    acc.y += __shfl_xor(acc.y, 1);
    if (h == 0) {
        float dv = dinv[n];
        float z0 = fmaf(dv, acc.x, b[0]);
        float z1 = fmaf(dv, acc.y, b[1]);
        float m = fmaxf(z0, z1);
        float lse = m + logf(expf(z0 - m) + expf(z1 - m));
        out[(size_t)n * 2 + 0] = z0 - lse;
        out[(size_t)n * 2 + 1] = z1 - lse;
    }
}

extern "C" void kernel_launch(void* const* d_in, const int* in_sizes, int n_in,
                              void* d_out, int out_size, void* d_ws, size_t ws_size,
                              hipStream_t stream) {
    const float* x  = (const float*)d_in[0];
    const int*   ei = (const int*)d_in[1];
    const float* W1 = (const float*)d_in[2];
    const float* b1 = (const float*)d_in[3];
    const float* W2 = (const float*)d_in[4];
    const float* b2 = (const float*)d_in[5];
    const float* W3 = (const float*)d_in[6];
    const float* b3 = (const float*)d_in[7];
    float* out = (float*)d_out;

    const int N = in_sizes[0] / 165;  // 100000
    const int E = in_sizes[1] / 2;    // 3200000
    const int* src = ei;
    const int* dst = ei + E;
    const int nbuk = (N + NPB - 1) >> LOG_NPB;  // 391
    const int G4 = ((size_t)N * 4 + NT - 1) / NT;  // 4 lanes/node dispatches
    const int G2 = ((size_t)N * 2 + NT - 1) / NT;  // 2 lanes/node dispatches

    char* p = (char*)d_ws;
    int* cursor8   = (int*)p;      p += (size_t)NREP * MAXBUK * 4;
    unsigned* ebuf = (unsigned*)p; p += (size_t)nbuk * BSTRIDE * 4;
    int* esrc      = (int*)p;      p += (size_t)nbuk * BSTRIDE * 4;
    int* rowptr    = (int*)p;      p += (size_t)N * 4;
    int* rowcnt    = (int*)p;      p += (size_t)N * 4;
    float* dinv    = (float*)p;    p += (size_t)N * 4;
    uint4* hs1b    = (uint4*)p;    p += (size_t)N * 4 * 16;  // bf16 [N][4]uint4
    uint4* hs2b    = (uint4*)p;    p += (size_t)N * 2 * 16;  // bf16 [N][2]uint4
    float* hs3     = (float*)p;    p += (size_t)N * 2 * 4;   // f32 [N][2]

    (void)hipMemsetAsync(cursor8, 0, (size_t)NREP * MAXBUK * sizeof(int), stream);
    place_kernel<<<(E + EPB_B - 1) / EPB_B, NT, 0, stream>>>(src, dst, cursor8, ebuf, E, nbuk);
    sort_kernel<<<nbuk, NT, 0, stream>>>(ebuf, cursor8, esrc, rowptr, rowcnt, dinv, N);

    // Layer 1: 165 -> 32 MFMA, bf16 messages (one 64B line per node)
    gemm1_mfma<<<((N + 15) / 16 + 3) / 4, NT, 0, stream>>>(x, W1, dinv, hs1b, N);

    // Layer 1 gather + layer 2 GEMM fused (4 lanes/node)
    g1g2_kernel<<<G4, NT, 0, stream>>>(hs1b, esrc, rowptr, rowcnt, dinv, b1, W2, hs2b, N);

    // Layer 2 gather + layer 3 GEMM fused (4 lanes/node)
    g2g3_kernel<<<G4, NT, 0, stream>>>(hs2b, esrc, rowptr, rowcnt, dinv, b2, W3, hs3, N);

    // Layer 3 gather + bias + log_softmax (2 lanes/node)
    final_kernel<<<G2, NT, 0, stream>>>(hs3, esrc, rowptr, rowcnt, dinv, b3, out, N);
}